// Round 1
// baseline (295.777 us; speedup 1.0000x reference)
//
#include <hip/hip_runtime.h>
#include <hip/hip_bf16.h>

#define NB 128
#define NQ 900
#define NT 256
#define NG 20

__device__ __forceinline__ float clamp01(float v) {
    return fminf(fmaxf(v, 0.0f), 1.0f);
}

// ---------------------------------------------------------------------------
// Kernel A: per-batch greedy matching + bbox L1 + GIoU losses + span scatter.
// One block per batch. Each thread owns pred rows q = tid + 256*r (r=0..3) in
// registers; each greedy step recomputes the IoU column for target g and does
// a block argmax with first-index tie-break (matches jnp.argmax semantics).
// ---------------------------------------------------------------------------
__global__ __launch_bounds__(256) void match_kernel(
    const float4* __restrict__ pred_boxes,  // [B*Q] cxcywh
    const float4* __restrict__ tgt_boxes,   // [B*G] cxcywh
    const int2*   __restrict__ tokens,      // [B*G] (start, end)
    int*          __restrict__ spans,       // [B*Q] packed start|end<<16 (0 = empty)
    float*        __restrict__ accum)       // [0]=bbox sum, [1]=giou sum
{
    const int b   = blockIdx.x;
    const int tid = threadIdx.x;

    __shared__ float tx1[NG], ty1[NG], tx2[NG], ty2[NG], ta[NG];
    __shared__ int   matched[NG];
    __shared__ float red_v[4];
    __shared__ int   red_i[4];

    if (tid < NG) {
        float4 tb = tgt_boxes[b * NG + tid];
        float x1 = tb.x - 0.5f * tb.z, y1 = tb.y - 0.5f * tb.w;
        float x2 = tb.x + 0.5f * tb.z, y2 = tb.y + 0.5f * tb.w;
        tx1[tid] = x1; ty1[tid] = y1; tx2[tid] = x2; ty2[tid] = y2;
        ta[tid]  = (x2 - x1) * (y2 - y1);
    }
    __syncthreads();

    // Load this thread's pred rows into registers.
    float px1[4], py1[4], px2[4], py2[4], pa[4];
    int avail_mask = 0;
    #pragma unroll
    for (int r = 0; r < 4; ++r) {
        int q = tid + 256 * r;
        if (q < NQ) {
            float4 pb = pred_boxes[b * NQ + q];
            px1[r] = pb.x - 0.5f * pb.z; py1[r] = pb.y - 0.5f * pb.w;
            px2[r] = pb.x + 0.5f * pb.z; py2[r] = pb.y + 0.5f * pb.w;
            pa[r]  = (px2[r] - px1[r]) * (py2[r] - py1[r]);
            avail_mask |= (1 << r);
        }
    }

    for (int g = 0; g < NG; ++g) {
        float gx1 = tx1[g], gy1 = ty1[g], gx2 = tx2[g], gy2 = ty2[g], ga = ta[g];
        float bv = -2.0f;
        int   bi = 0x7fffffff;
        #pragma unroll
        for (int r = 0; r < 4; ++r) {
            if (avail_mask & (1 << r)) {
                float ix1 = fmaxf(px1[r], gx1), iy1 = fmaxf(py1[r], gy1);
                float ix2 = fminf(px2[r], gx2), iy2 = fminf(py2[r], gy2);
                float iw = fmaxf(ix2 - ix1, 0.0f), ih = fmaxf(iy2 - iy1, 0.0f);
                float inter = iw * ih;
                float uni   = pa[r] + ga - inter;
                float v     = inter / uni;
                int   q     = tid + 256 * r;
                if (v > bv) { bv = v; bi = q; }   // strict > keeps first max (q ascending)
            }
        }
        // Wave-level argmax reduce: larger value wins; on tie, smaller index.
        #pragma unroll
        for (int off = 32; off > 0; off >>= 1) {
            float ov = __shfl_down(bv, off);
            int   oi = __shfl_down(bi, off);
            if (ov > bv || (ov == bv && oi < bi)) { bv = ov; bi = oi; }
        }
        if ((tid & 63) == 0) { red_v[tid >> 6] = bv; red_i[tid >> 6] = bi; }
        __syncthreads();
        if (tid == 0) {
            float fv = red_v[0]; int fi = red_i[0];
            #pragma unroll
            for (int w = 1; w < 4; ++w) {
                if (red_v[w] > fv || (red_v[w] == fv && red_i[w] < fi)) {
                    fv = red_v[w]; fi = red_i[w];
                }
            }
            matched[g] = fi;
        }
        __syncthreads();
        int best = matched[g];
        if ((best & 255) == tid) avail_mask &= ~(1 << (best >> 8));  // remove matched row
    }

    // Epilogue: box losses + span scatter for the 20 matched pairs.
    if (tid < NG) {
        int g = tid;
        int q = matched[g];
        float4 pb = pred_boxes[b * NQ + q];
        float4 tb = tgt_boxes[b * NG + g];
        float lb = fabsf(pb.x - tb.x) + fabsf(pb.y - tb.y) +
                   fabsf(pb.z - tb.z) + fabsf(pb.w - tb.w);

        // matched xyxy, validated (x2>=x1+eps then clip to [0,1])
        float mx1 = pb.x - 0.5f * pb.z, my1 = pb.y - 0.5f * pb.w;
        float mx2 = pb.x + 0.5f * pb.z, my2 = pb.y + 0.5f * pb.w;
        mx2 = fmaxf(mx2, mx1 + 1e-6f);  my2 = fmaxf(my2, my1 + 1e-6f);
        mx1 = clamp01(mx1); my1 = clamp01(my1); mx2 = clamp01(mx2); my2 = clamp01(my2);

        // tgt xyxy, validated
        float gx1 = tx1[g], gy1 = ty1[g];
        float gx2 = fmaxf(tx2[g], gx1 + 1e-6f);
        float gy2 = fmaxf(ty2[g], gy1 + 1e-6f);
        gx1 = clamp01(gx1); gy1 = clamp01(gy1); gx2 = clamp01(gx2); gy2 = clamp01(gy2);

        // GIoU
        float a1 = (mx2 - mx1) * (my2 - my1);
        float a2 = (gx2 - gx1) * (gy2 - gy1);
        float ix1 = fmaxf(mx1, gx1), iy1 = fmaxf(my1, gy1);
        float ix2 = fminf(mx2, gx2), iy2 = fminf(my2, gy2);
        float iw = fmaxf(ix2 - ix1, 0.0f), ih = fmaxf(iy2 - iy1, 0.0f);
        float inter = iw * ih;
        float uni   = a1 + a2 - inter;
        float iou   = inter / uni;
        float cx1 = fminf(mx1, gx1), cy1 = fminf(my1, gy1);
        float cx2 = fmaxf(mx2, gx2), cy2 = fmaxf(my2, gy2);
        float cw = fmaxf(cx2 - cx1, 0.0f), ch = fmaxf(cy2 - cy1, 0.0f);
        float ac = cw * ch;
        float giou = iou - (ac - uni) / ac;

        atomicAdd(&accum[0], lb);
        atomicAdd(&accum[1], 1.0f - giou);

        int2 tk = tokens[b * NG + g];
        spans[b * NQ + q] = tk.x | (tk.y << 16);
    }
}

// ---------------------------------------------------------------------------
// Kernel B: sigmoid focal loss over all B*Q*T logits. One wave per (b,q) row
// (64 lanes x float4 = 256 logits). Targets derived from the packed span.
// 1 exp + 1 log per element; gamma=2 is just a square.
// ---------------------------------------------------------------------------
__device__ __forceinline__ float focal_term(float x, bool pos) {
    float ax  = fabsf(x);
    float em  = __expf(-ax);              // e^{-|x|}
    float ce  = fmaxf(x, 0.0f) - (pos ? x : 0.0f) + __logf(1.0f + em);
    float inv = 1.0f / (1.0f + em);
    float va  = inv;                      // p      if x>=0, 1-p if x<0
    float vb  = em * inv;                 // 1-p    if x>=0, p   if x<0
    bool  s   = (x >= 0.0f);
    float omp = (pos == s) ? vb : va;     // 1 - p_t
    float at  = pos ? 0.25f : 0.75f;
    return at * ce * omp * omp;
}

__global__ __launch_bounds__(256) void focal_kernel(
    const float4* __restrict__ logits,   // [B*Q*T/4]
    const int*    __restrict__ spans,    // [B*Q]
    float*        __restrict__ accum)    // [2] = class sum
{
    const int lane   = threadIdx.x & 63;
    const int wave   = (blockIdx.x * blockDim.x + threadIdx.x) >> 6;
    const int nwaves = (gridDim.x * blockDim.x) >> 6;

    float sum = 0.0f;
    for (int row = wave; row < NB * NQ; row += nwaves) {
        int sp = spans[row];
        int s  = sp & 0xffff;
        int e  = (sp >> 16) & 0xffff;
        float4 v = logits[row * (NT / 4) + lane];
        int t0 = lane * 4;
        sum += focal_term(v.x, (t0     >= s) && (t0     < e));
        sum += focal_term(v.y, (t0 + 1 >= s) && (t0 + 1 < e));
        sum += focal_term(v.z, (t0 + 2 >= s) && (t0 + 2 < e));
        sum += focal_term(v.w, (t0 + 3 >= s) && (t0 + 3 < e));
    }
    #pragma unroll
    for (int off = 32; off > 0; off >>= 1) sum += __shfl_down(sum, off);
    if (lane == 0) atomicAdd(&accum[2], sum);
}

// ---------------------------------------------------------------------------
// Kernel C: finalize — apply coefficients, write 4 outputs.
// ---------------------------------------------------------------------------
__global__ void finalize_kernel(const float* __restrict__ accum,
                                float* __restrict__ out)
{
    const float num_boxes = (float)(NB * NG);               // 2560
    float lb = 5.0f * accum[0] / num_boxes;
    float lg = 2.0f * accum[1] / num_boxes;
    float lc = 1.0f * (accum[2] / (float)(NQ * NT)) / num_boxes;
    out[0] = lb;
    out[1] = lg;
    out[2] = lc;
    out[3] = lb + lg + lc;
}

extern "C" void kernel_launch(void* const* d_in, const int* in_sizes, int n_in,
                              void* d_out, int out_size, void* d_ws, size_t ws_size,
                              hipStream_t stream) {
    const float4* pred_logits4 = (const float4*)d_in[0];  // (B,Q,T) f32
    const float4* pred_boxes4  = (const float4*)d_in[1];  // (B,Q,4) f32
    const float4* tgt_boxes4   = (const float4*)d_in[2];  // (B,G,4) f32
    const int2*   tokens2      = (const int2*)d_in[3];    // (B,G,2) i32

    float* accum = (float*)d_ws;                          // 4 floats
    int*   spans = (int*)((char*)d_ws + 16);              // B*Q packed ints

    // Zero accumulators + spans (0 packed span == empty == target 0).
    hipMemsetAsync(d_ws, 0, 16 + (size_t)NB * NQ * sizeof(int), stream);

    match_kernel<<<NB, 256, 0, stream>>>(pred_boxes4, tgt_boxes4, tokens2,
                                         spans, accum);
    focal_kernel<<<2048, 256, 0, stream>>>(pred_logits4, spans, accum);
    finalize_kernel<<<1, 1, 0, stream>>>(accum, (float*)d_out);
}

// Round 2
// 237.898 us; speedup vs baseline: 1.2433x; 1.2433x over previous
//
#include <hip/hip_runtime.h>
#include <hip/hip_bf16.h>

#define NB 128
#define NQ 900
#define NT 256
#define NG 20
#define NR 15          // pred rows per lane in match kernel: 64*15 >= 900
#define FWAVES 7200    // focal_neg waves: 115200 rows / 4 rows-per-group / 4 iters

__device__ __forceinline__ float clamp01(float v) {
    return fminf(fmaxf(v, 0.0f), 1.0f);
}

// ---------------------------------------------------------------------------
// focal(x, target=0) WITHOUT the alpha factor (0.75 folded into finalize):
//   ce = max(x,0) + log1p(e^{-|x|});  1-p_t = p = sigmoid(x);  ret = ce*p^2
// ---------------------------------------------------------------------------
__device__ __forceinline__ float focal_neg_term(float x) {
    float ax  = fabsf(x);
    float em  = __expf(-ax);
    float a1  = 1.0f + em;
    float ce  = fmaxf(x, 0.0f) + __logf(a1);
    float inv = __builtin_amdgcn_rcpf(a1);
    float p   = (x >= 0.0f) ? inv : em * inv;
    return ce * p * p;
}

// focal(x,1) - focal(x,0), full alpha factors included.
__device__ __forceinline__ float focal_delta_term(float x) {
    float ax     = fabsf(x);
    float em     = __expf(-ax);
    float a1     = 1.0f + em;
    float lg     = __logf(a1);
    float ce0    = fmaxf(x, 0.0f) + lg;
    float ce1    = ce0 - x;
    float inv    = __builtin_amdgcn_rcpf(a1);
    float em_inv = em * inv;
    float p      = (x >= 0.0f) ? inv : em_inv;   // sigmoid(x)
    float omp    = (x >= 0.0f) ? em_inv : inv;   // 1 - p
    return 0.25f * ce1 * omp * omp - 0.75f * ce0 * p * p;
}

// ---------------------------------------------------------------------------
// Kernel 1: sum of focal_neg_term over all B*Q*T logits (target==0 baseline).
// Wave w handles row-groups {w, w+7200, w+14400, w+21600}, 4 rows per group,
// 4 independent float4 loads (4 KB) in flight per iteration. Per-block LDS
// reduce -> 1 atomic per block.
// ---------------------------------------------------------------------------
__global__ __launch_bounds__(256) void focal_neg_kernel(
    const float4* __restrict__ logits,   // [B*Q*T/4]
    float*        __restrict__ accum)    // accum[2] += sum
{
    const int lane = threadIdx.x & 63;
    const int wav  = threadIdx.x >> 6;
    const int gw   = (blockIdx.x * blockDim.x + threadIdx.x) >> 6;

    float sum = 0.0f;
    #pragma unroll
    for (int i = 0; i < 4; ++i) {
        int group = gw + i * FWAVES;        // 0..28799
        int row0  = group * 4;
        float4 v0 = logits[(row0 + 0) * (NT / 4) + lane];
        float4 v1 = logits[(row0 + 1) * (NT / 4) + lane];
        float4 v2 = logits[(row0 + 2) * (NT / 4) + lane];
        float4 v3 = logits[(row0 + 3) * (NT / 4) + lane];
        sum += focal_neg_term(v0.x) + focal_neg_term(v0.y) +
               focal_neg_term(v0.z) + focal_neg_term(v0.w);
        sum += focal_neg_term(v1.x) + focal_neg_term(v1.y) +
               focal_neg_term(v1.z) + focal_neg_term(v1.w);
        sum += focal_neg_term(v2.x) + focal_neg_term(v2.y) +
               focal_neg_term(v2.z) + focal_neg_term(v2.w);
        sum += focal_neg_term(v3.x) + focal_neg_term(v3.y) +
               focal_neg_term(v3.z) + focal_neg_term(v3.w);
    }
    #pragma unroll
    for (int off = 32; off > 0; off >>= 1) sum += __shfl_down(sum, off);

    __shared__ float wsum[4];
    if (lane == 0) wsum[wav] = sum;
    __syncthreads();
    if (threadIdx.x == 0)
        atomicAdd(&accum[2], wsum[0] + wsum[1] + wsum[2] + wsum[3]);
}

// ---------------------------------------------------------------------------
// Kernel 2: per-batch greedy matching + bbox L1 + GIoU. ONE WAVE per batch —
// no __syncthreads in the 20-step loop. Lane l owns pred rows q = l + 64*r,
// r = 0..14, in registers. Butterfly argmax: larger IoU wins, ties -> smaller
// q (jnp.argmax first-occurrence). IoU uses exact f32 division.
// ---------------------------------------------------------------------------
__global__ __launch_bounds__(64) void match_kernel(
    const float4* __restrict__ pred_boxes,   // [B*Q] cxcywh
    const float4* __restrict__ tgt_boxes,    // [B*G] cxcywh
    const int2*   __restrict__ tokens,       // [B*G] (start, end)
    int2*         __restrict__ matched_info, // [B*G] {row, start|end<<16}
    float*        __restrict__ accum)        // [0]=bbox sum, [1]=giou sum
{
    const int b    = blockIdx.x;
    const int lane = threadIdx.x;

    __shared__ float tx1s[NG], ty1s[NG], tx2s[NG], ty2s[NG], tas[NG];

    if (lane < NG) {
        float4 tb = tgt_boxes[b * NG + lane];
        float x1 = tb.x - 0.5f * tb.z, y1 = tb.y - 0.5f * tb.w;
        float x2 = tb.x + 0.5f * tb.z, y2 = tb.y + 0.5f * tb.w;
        tx1s[lane] = x1; ty1s[lane] = y1; tx2s[lane] = x2; ty2s[lane] = y2;
        tas[lane]  = (x2 - x1) * (y2 - y1);
    }
    __syncthreads();   // single wave: near-free, guarantees LDS visibility

    float px1[NR], py1[NR], px2[NR], py2[NR], pa[NR];
    int avail = 0;
    #pragma unroll
    for (int r = 0; r < NR; ++r) {
        int q = lane + 64 * r;
        if (q < NQ) {
            float4 pb = pred_boxes[b * NQ + q];
            px1[r] = pb.x - 0.5f * pb.z; py1[r] = pb.y - 0.5f * pb.w;
            px2[r] = pb.x + 0.5f * pb.z; py2[r] = pb.y + 0.5f * pb.w;
            pa[r]  = (px2[r] - px1[r]) * (py2[r] - py1[r]);
            avail |= (1 << r);
        } else {
            px1[r] = 0.0f; py1[r] = 0.0f; px2[r] = 0.0f; py2[r] = 0.0f;
            pa[r] = 0.0f;
        }
    }

    int my_q = 0;   // matched q for g == lane (lanes 0..19)
    for (int g = 0; g < NG; ++g) {
        float gx1 = tx1s[g], gy1 = ty1s[g], gx2 = tx2s[g], gy2 = ty2s[g];
        float ga  = tas[g];
        float bv = -2.0f;
        int   bi = 0x7fffffff;
        #pragma unroll
        for (int r = 0; r < NR; ++r) {
            float ix1 = fmaxf(px1[r], gx1), iy1 = fmaxf(py1[r], gy1);
            float ix2 = fminf(px2[r], gx2), iy2 = fminf(py2[r], gy2);
            float iw = fmaxf(ix2 - ix1, 0.0f), ih = fmaxf(iy2 - iy1, 0.0f);
            float inter = iw * ih;
            float v = inter / (pa[r] + ga - inter);   // exact div, matches ref
            bool ok = (avail >> r) & 1;
            v = ok ? v : -1.0f;                       // also kills q>=900 NaNs
            int q = lane + 64 * r;
            if (v > bv) { bv = v; bi = q; }           // strict >: first max per lane
        }
        #pragma unroll
        for (int off = 1; off < 64; off <<= 1) {
            float ov = __shfl_xor(bv, off);
            int   oi = __shfl_xor(bi, off);
            if (ov > bv || (ov == bv && oi < bi)) { bv = ov; bi = oi; }
        }
        // all lanes now agree on (bv, bi)
        if (lane == g) my_q = bi;
        if ((bi & 63) == lane) avail &= ~(1 << (bi >> 6));  // remove matched row
    }

    // Epilogue: bbox L1 + GIoU for g = lane < 20, wave-reduce, 2 atomics.
    float lb = 0.0f, lgi = 0.0f;
    if (lane < NG) {
        int g = lane, q = my_q;
        float4 pb = pred_boxes[b * NQ + q];
        float4 tb = tgt_boxes[b * NG + g];
        lb = fabsf(pb.x - tb.x) + fabsf(pb.y - tb.y) +
             fabsf(pb.z - tb.z) + fabsf(pb.w - tb.w);

        float mx1 = pb.x - 0.5f * pb.z, my1 = pb.y - 0.5f * pb.w;
        float mx2 = pb.x + 0.5f * pb.z, my2 = pb.y + 0.5f * pb.w;
        mx2 = fmaxf(mx2, mx1 + 1e-6f);  my2 = fmaxf(my2, my1 + 1e-6f);
        mx1 = clamp01(mx1); my1 = clamp01(my1); mx2 = clamp01(mx2); my2 = clamp01(my2);

        float gx1 = tx1s[g], gy1 = ty1s[g];
        float gx2 = fmaxf(tx2s[g], gx1 + 1e-6f);
        float gy2 = fmaxf(ty2s[g], gy1 + 1e-6f);
        gx1 = clamp01(gx1); gy1 = clamp01(gy1); gx2 = clamp01(gx2); gy2 = clamp01(gy2);

        float a1 = (mx2 - mx1) * (my2 - my1);
        float a2 = (gx2 - gx1) * (gy2 - gy1);
        float ix1 = fmaxf(mx1, gx1), iy1 = fmaxf(my1, gy1);
        float ix2 = fminf(mx2, gx2), iy2 = fminf(my2, gy2);
        float iw = fmaxf(ix2 - ix1, 0.0f), ih = fmaxf(iy2 - iy1, 0.0f);
        float inter = iw * ih;
        float uni   = a1 + a2 - inter;
        float iou   = inter / uni;
        float cx1 = fminf(mx1, gx1), cy1 = fminf(my1, gy1);
        float cx2 = fmaxf(mx2, gx2), cy2 = fmaxf(my2, gy2);
        float ac  = fmaxf(cx2 - cx1, 0.0f) * fmaxf(cy2 - cy1, 0.0f);
        lgi = 1.0f - (iou - (ac - uni) / ac);

        int2 tk = tokens[b * NG + g];
        matched_info[b * NG + g] = make_int2(b * NQ + q, tk.x | (tk.y << 16));
    }
    #pragma unroll
    for (int off = 32; off > 0; off >>= 1) {
        lb  += __shfl_down(lb,  off);
        lgi += __shfl_down(lgi, off);
    }
    if (lane == 0) {
        atomicAdd(&accum[0], lb);
        atomicAdd(&accum[1], lgi);
    }
}

// ---------------------------------------------------------------------------
// Kernel 3: correction over the 2560 matched rows only:
//   sum over span elements of [focal(x,1) - focal(x,0)]  -> accum[3]
// One wave per matched entry.
// ---------------------------------------------------------------------------
__global__ __launch_bounds__(256) void correction_kernel(
    const float4* __restrict__ logits,
    const int2*   __restrict__ matched_info,  // [B*G]
    float*        __restrict__ accum)
{
    const int lane = threadIdx.x & 63;
    const int wav  = threadIdx.x >> 6;
    const int e    = (blockIdx.x * blockDim.x + threadIdx.x) >> 6;  // 0..2559

    int2 info = matched_info[e];
    int row = info.x;
    int s   = info.y & 0xffff;
    int en  = (info.y >> 16) & 0xffff;

    float4 v = logits[row * (NT / 4) + lane];
    int t0 = lane * 4;
    float d = 0.0f;
    if (t0     >= s && t0     < en) d += focal_delta_term(v.x);
    if (t0 + 1 >= s && t0 + 1 < en) d += focal_delta_term(v.y);
    if (t0 + 2 >= s && t0 + 2 < en) d += focal_delta_term(v.z);
    if (t0 + 3 >= s && t0 + 3 < en) d += focal_delta_term(v.w);

    #pragma unroll
    for (int off = 32; off > 0; off >>= 1) d += __shfl_down(d, off);

    __shared__ float wsum[4];
    if (lane == 0) wsum[wav] = d;
    __syncthreads();
    if (threadIdx.x == 0)
        atomicAdd(&accum[3], wsum[0] + wsum[1] + wsum[2] + wsum[3]);
}

// ---------------------------------------------------------------------------
// Kernel 4: finalize.
// ---------------------------------------------------------------------------
__global__ void finalize_kernel(const float* __restrict__ accum,
                                float* __restrict__ out)
{
    const float num_boxes = (float)(NB * NG);               // 2560
    float lb = 5.0f * accum[0] / num_boxes;
    float lg = 2.0f * accum[1] / num_boxes;
    float cls_sum = 0.75f * accum[2] + accum[3];
    float lc = (cls_sum / (float)(NQ * NT)) / num_boxes;
    out[0] = lb;
    out[1] = lg;
    out[2] = lc;
    out[3] = lb + lg + lc;
}

extern "C" void kernel_launch(void* const* d_in, const int* in_sizes, int n_in,
                              void* d_out, int out_size, void* d_ws, size_t ws_size,
                              hipStream_t stream) {
    const float4* pred_logits4 = (const float4*)d_in[0];  // (B,Q,T) f32
    const float4* pred_boxes4  = (const float4*)d_in[1];  // (B,Q,4) f32
    const float4* tgt_boxes4   = (const float4*)d_in[2];  // (B,G,4) f32
    const int2*   tokens2      = (const int2*)d_in[3];    // (B,G,2) i32

    float* accum        = (float*)d_ws;                   // 4 floats
    int2*  matched_info = (int2*)((char*)d_ws + 16);      // B*G int2

    hipMemsetAsync(d_ws, 0, 16, stream);                  // zero accumulators

    focal_neg_kernel<<<1800, 256, 0, stream>>>(pred_logits4, accum);
    match_kernel<<<NB, 64, 0, stream>>>(pred_boxes4, tgt_boxes4, tokens2,
                                        matched_info, accum);
    correction_kernel<<<640, 256, 0, stream>>>(pred_logits4, matched_info, accum);
    finalize_kernel<<<1, 1, 0, stream>>>(accum, (float*)d_out);
}

// Round 3
// 184.579 us; speedup vs baseline: 1.6024x; 1.2889x over previous
//
#include <hip/hip_runtime.h>
#include <hip/hip_bf16.h>

#define NB 128
#define NQ 900
#define NT 256
#define NG 20
#define NR 15                 // pred rows per lane in match: 64*15 >= 900
#define FOCAL_BLOCKS 1800
#define MATCH_BLOCKS 128
#define TOTAL_BLOCKS (FOCAL_BLOCKS + MATCH_BLOCKS)
#define FWAVES (FOCAL_BLOCKS * 4)   // 7200 focal waves; x4 groups x4 rows = 115200 rows

// ws layout (floats): [0,7200) focal per-wave partials
//                     [7200,7328) bbox per-batch, [7328,7456) giou, [7456,7584) delta
#define WS_BB 7200
#define WS_GI 7328
#define WS_DL 7456

__device__ __forceinline__ float clamp01(float v) {
    return fminf(fmaxf(v, 0.0f), 1.0f);
}

// focal(x, target=0) WITHOUT the 0.75 alpha (folded into finalize).
__device__ __forceinline__ float focal_neg_term(float x) {
    float ax  = fabsf(x);
    float em  = __expf(-ax);
    float a1  = 1.0f + em;
    float ce  = fmaxf(x, 0.0f) + __logf(a1);
    float inv = __builtin_amdgcn_rcpf(a1);
    float p   = (x >= 0.0f) ? inv : em * inv;
    return ce * p * p;
}

// focal(x,1) - focal(x,0), full alpha factors included.
__device__ __forceinline__ float focal_delta_term(float x) {
    float ax     = fabsf(x);
    float em     = __expf(-ax);
    float a1     = 1.0f + em;
    float lg     = __logf(a1);
    float ce0    = fmaxf(x, 0.0f) + lg;
    float ce1    = ce0 - x;
    float inv    = __builtin_amdgcn_rcpf(a1);
    float em_inv = em * inv;
    float p      = (x >= 0.0f) ? inv : em_inv;   // sigmoid(x)
    float omp    = (x >= 0.0f) ? em_inv : inv;   // 1 - p
    return 0.25f * ce1 * omp * omp - 0.75f * ce0 * p * p;
}

// ---------------------------------------------------------------------------
// Fused kernel. Blocks [0,MATCH_BLOCKS): per-batch greedy match + bbox L1 +
// GIoU + span focal-correction, single active wave, no LDS, no atomics.
// Blocks [MATCH_BLOCKS, TOTAL): focal(target=0) baseline over all logits,
// per-wave partial to ws.
// ---------------------------------------------------------------------------
__global__ __launch_bounds__(256) void main_kernel(
    const float4* __restrict__ logits,      // [B*Q*T/4]
    const float4* __restrict__ pred_boxes,  // [B*Q] cxcywh
    const float4* __restrict__ tgt_boxes,   // [B*G] cxcywh
    const int2*   __restrict__ tokens,      // [B*G] (start, end)
    float*        __restrict__ ws)          // partials, see layout above
{
    if (blockIdx.x < MATCH_BLOCKS) {
        // ----------------- match path: one wave per batch -----------------
        if (threadIdx.x >= 64) return;        // waves 1..3 idle; no syncthreads used
        const int b    = blockIdx.x;
        const int lane = threadIdx.x;

        // Each lane owns pred rows q = lane + 64*r in registers.
        float px1[NR], py1[NR], px2[NR], py2[NR], pa[NR];
        int avail = 0;
        #pragma unroll
        for (int r = 0; r < NR; ++r) {
            int q = lane + 64 * r;
            if (q < NQ) {
                float4 pb = pred_boxes[b * NQ + q];
                px1[r] = pb.x - 0.5f * pb.z; py1[r] = pb.y - 0.5f * pb.w;
                px2[r] = pb.x + 0.5f * pb.z; py2[r] = pb.y + 0.5f * pb.w;
                pa[r]  = (px2[r] - px1[r]) * (py2[r] - py1[r]);
                avail |= (1 << r);
            } else {
                px1[r] = 0.0f; py1[r] = 0.0f; px2[r] = 0.0f; py2[r] = 0.0f;
                pa[r] = 0.0f;
            }
        }

        int my_q = 0;   // matched q for g == lane (lanes 0..19)
        for (int g = 0; g < NG; ++g) {
            float4 tb = tgt_boxes[b * NG + g];          // broadcast load (L1)
            float gx1 = tb.x - 0.5f * tb.z, gy1 = tb.y - 0.5f * tb.w;
            float gx2 = tb.x + 0.5f * tb.z, gy2 = tb.y + 0.5f * tb.w;
            float ga  = (gx2 - gx1) * (gy2 - gy1);
            float bv = -2.0f;
            int   bi = 0x7fffffff;
            #pragma unroll
            for (int r = 0; r < NR; ++r) {
                float ix1 = fmaxf(px1[r], gx1), iy1 = fmaxf(py1[r], gy1);
                float ix2 = fminf(px2[r], gx2), iy2 = fminf(py2[r], gy2);
                float iw = fmaxf(ix2 - ix1, 0.0f), ih = fmaxf(iy2 - iy1, 0.0f);
                float inter = iw * ih;
                float v = inter / (pa[r] + ga - inter);   // exact div, matches ref
                bool ok = (avail >> r) & 1;
                v = ok ? v : -1.0f;                       // also kills q>=900 NaNs
                int q = lane + 64 * r;
                if (v > bv) { bv = v; bi = q; }           // strict >: first max per lane
            }
            #pragma unroll
            for (int off = 1; off < 64; off <<= 1) {
                float ov = __shfl_xor(bv, off);
                int   oi = __shfl_xor(bi, off);
                if (ov > bv || (ov == bv && oi < bi)) { bv = ov; bi = oi; }
            }
            if (lane == g) my_q = bi;
            if ((bi & 63) == lane) avail &= ~(1 << (bi >> 6));  // remove matched row
        }

        // Epilogue: bbox L1 + GIoU + span focal-correction for g = lane < 20.
        float lb = 0.0f, lgi = 0.0f, dl = 0.0f;
        if (lane < NG) {
            int g = lane, q = my_q;
            float4 pb = pred_boxes[b * NQ + q];
            float4 tb = tgt_boxes[b * NG + g];
            lb = fabsf(pb.x - tb.x) + fabsf(pb.y - tb.y) +
                 fabsf(pb.z - tb.z) + fabsf(pb.w - tb.w);

            float mx1 = pb.x - 0.5f * pb.z, my1 = pb.y - 0.5f * pb.w;
            float mx2 = pb.x + 0.5f * pb.z, my2 = pb.y + 0.5f * pb.w;
            mx2 = fmaxf(mx2, mx1 + 1e-6f);  my2 = fmaxf(my2, my1 + 1e-6f);
            mx1 = clamp01(mx1); my1 = clamp01(my1);
            mx2 = clamp01(mx2); my2 = clamp01(my2);

            float gx1 = tb.x - 0.5f * tb.z, gy1 = tb.y - 0.5f * tb.w;
            float gx2 = tb.x + 0.5f * tb.z, gy2 = tb.y + 0.5f * tb.w;
            gx2 = fmaxf(gx2, gx1 + 1e-6f);  gy2 = fmaxf(gy2, gy1 + 1e-6f);
            gx1 = clamp01(gx1); gy1 = clamp01(gy1);
            gx2 = clamp01(gx2); gy2 = clamp01(gy2);

            float a1 = (mx2 - mx1) * (my2 - my1);
            float a2 = (gx2 - gx1) * (gy2 - gy1);
            float ix1 = fmaxf(mx1, gx1), iy1 = fmaxf(my1, gy1);
            float ix2 = fminf(mx2, gx2), iy2 = fminf(my2, gy2);
            float iw = fmaxf(ix2 - ix1, 0.0f), ih = fmaxf(iy2 - iy1, 0.0f);
            float inter = iw * ih;
            float uni   = a1 + a2 - inter;
            float iou   = inter / uni;
            float cx1 = fminf(mx1, gx1), cy1 = fminf(my1, gy1);
            float cx2 = fmaxf(mx2, gx2), cy2 = fmaxf(my2, gy2);
            float ac  = fmaxf(cx2 - cx1, 0.0f) * fmaxf(cy2 - cy1, 0.0f);
            lgi = 1.0f - (iou - (ac - uni) / ac);

            // Span correction: sum focal(x,1)-focal(x,0) over the <=5 span tokens.
            int2 tk = tokens[b * NG + g];
            const float* rowp = (const float*)logits + (size_t)(b * NQ + q) * NT;
            for (int t = tk.x; t < tk.y; ++t) dl += focal_delta_term(rowp[t]);
        }
        #pragma unroll
        for (int off = 32; off > 0; off >>= 1) {
            lb  += __shfl_down(lb,  off);
            lgi += __shfl_down(lgi, off);
            dl  += __shfl_down(dl,  off);
        }
        if (lane == 0) {
            ws[WS_BB + b] = lb;
            ws[WS_GI + b] = lgi;
            ws[WS_DL + b] = dl;
        }
    } else {
        // ----------------- focal(target=0) baseline path -----------------
        const int lane = threadIdx.x & 63;
        const int gw   = ((blockIdx.x - MATCH_BLOCKS) * 256 + threadIdx.x) >> 6;

        float sum = 0.0f;
        #pragma unroll
        for (int i = 0; i < 4; ++i) {
            int row0 = (gw + i * FWAVES) * 4;
            float4 v0 = logits[(row0 + 0) * (NT / 4) + lane];
            float4 v1 = logits[(row0 + 1) * (NT / 4) + lane];
            float4 v2 = logits[(row0 + 2) * (NT / 4) + lane];
            float4 v3 = logits[(row0 + 3) * (NT / 4) + lane];
            sum += focal_neg_term(v0.x) + focal_neg_term(v0.y) +
                   focal_neg_term(v0.z) + focal_neg_term(v0.w);
            sum += focal_neg_term(v1.x) + focal_neg_term(v1.y) +
                   focal_neg_term(v1.z) + focal_neg_term(v1.w);
            sum += focal_neg_term(v2.x) + focal_neg_term(v2.y) +
                   focal_neg_term(v2.z) + focal_neg_term(v2.w);
            sum += focal_neg_term(v3.x) + focal_neg_term(v3.y) +
                   focal_neg_term(v3.z) + focal_neg_term(v3.w);
        }
        #pragma unroll
        for (int off = 32; off > 0; off >>= 1) sum += __shfl_down(sum, off);
        if (lane == 0) ws[gw] = sum;    // unconditional per-wave partial
    }
}

// ---------------------------------------------------------------------------
// Finalize: one block sums 7200 focal partials + 3x128 match partials,
// applies coefficients, writes the 4 outputs.
// ---------------------------------------------------------------------------
__global__ __launch_bounds__(256) void finalize_kernel(
    const float* __restrict__ ws, float* __restrict__ out)
{
    const int tid  = threadIdx.x;
    const int lane = tid & 63;
    const int wav  = tid >> 6;

    float s_neg = 0.0f;
    for (int i = tid; i < FWAVES; i += 256) s_neg += ws[i];
    float s_bb = 0.0f, s_gi = 0.0f, s_dl = 0.0f;
    if (tid < NB) {
        s_bb = ws[WS_BB + tid];
        s_gi = ws[WS_GI + tid];
        s_dl = ws[WS_DL + tid];
    }
    #pragma unroll
    for (int off = 32; off > 0; off >>= 1) {
        s_neg += __shfl_down(s_neg, off);
        s_bb  += __shfl_down(s_bb,  off);
        s_gi  += __shfl_down(s_gi,  off);
        s_dl  += __shfl_down(s_dl,  off);
    }
    __shared__ float red[4][4];
    if (lane == 0) {
        red[0][wav] = s_neg; red[1][wav] = s_bb;
        red[2][wav] = s_gi;  red[3][wav] = s_dl;
    }
    __syncthreads();
    if (tid == 0) {
        float neg = red[0][0] + red[0][1] + red[0][2] + red[0][3];
        float bb  = red[1][0] + red[1][1] + red[1][2] + red[1][3];
        float gi  = red[2][0] + red[2][1] + red[2][2] + red[2][3];
        float dlt = red[3][0] + red[3][1] + red[3][2] + red[3][3];
        const float num_boxes = (float)(NB * NG);          // 2560
        float lb = 5.0f * bb / num_boxes;
        float lg = 2.0f * gi / num_boxes;
        float cls_sum = 0.75f * neg + dlt;
        float lc = (cls_sum / (float)(NQ * NT)) / num_boxes;
        out[0] = lb;
        out[1] = lg;
        out[2] = lc;
        out[3] = lb + lg + lc;
    }
}

extern "C" void kernel_launch(void* const* d_in, const int* in_sizes, int n_in,
                              void* d_out, int out_size, void* d_ws, size_t ws_size,
                              hipStream_t stream) {
    const float4* pred_logits4 = (const float4*)d_in[0];  // (B,Q,T) f32
    const float4* pred_boxes4  = (const float4*)d_in[1];  // (B,Q,4) f32
    const float4* tgt_boxes4   = (const float4*)d_in[2];  // (B,G,4) f32
    const int2*   tokens2      = (const int2*)d_in[3];    // (B,G,2) i32

    float* ws = (float*)d_ws;   // 7584 floats, all slots written every call

    main_kernel<<<TOTAL_BLOCKS, 256, 0, stream>>>(pred_logits4, pred_boxes4,
                                                  tgt_boxes4, tokens2, ws);
    finalize_kernel<<<1, 256, 0, stream>>>(ws, (float*)d_out);
}